// Round 1
// baseline (504.696 us; speedup 1.0000x reference)
//
#include <hip/hip_runtime.h>
#include <math.h>

// ---------------------------------------------------------------------------
// Kernel 1: logits[N][64] = x[N][1024] @ W[64][1024]^T + b, fp64 accumulation.
// Tile: 64 tokens x 64 experts per block, 256 threads, K-chunk = 128.
// LDS stores both tiles TRANSPOSED ([kk][row], stride 68 => 16B-aligned float4
// reads, ~2-way bank conflicts on compute reads).
// ---------------------------------------------------------------------------
__global__ __launch_bounds__(256) void logits_kernel(
    const float* __restrict__ x, const float* __restrict__ W,
    const float* __restrict__ b, float* __restrict__ logits,
    int N, int D) {
  const int DC = 128;
  __shared__ __attribute__((aligned(16))) float xs[128][68];
  __shared__ __attribute__((aligned(16))) float wsm[128][68];

  const int tid = threadIdx.x;
  const int tok0 = blockIdx.x * 64;
  const int tr = tid & 15;   // token group: tokens tr*4 .. tr*4+3
  const int tc = tid >> 4;   // expert group: experts tc*4 .. tc*4+3

  double acc[4][4];
#pragma unroll
  for (int i = 0; i < 4; ++i)
#pragma unroll
    for (int j = 0; j < 4; ++j) acc[i][j] = 0.0;

  for (int kc = 0; kc < D; kc += DC) {
    // ---- stage x-tile and W-tile (transposed) ----
#pragma unroll
    for (int it = 0; it < 8; ++it) {
      int idx4 = it * 256 + tid;       // 0..2047 float4 slots
      int row = idx4 >> 5;             // 0..63 (token / expert row)
      int c4  = idx4 & 31;             // float4 column within chunk
      float4 xv = *(const float4*)(x + (size_t)(tok0 + row) * D + kc + c4 * 4);
      float4 wv = *(const float4*)(W + (size_t)row * D + kc + c4 * 4);
      float xa[4] = {xv.x, xv.y, xv.z, xv.w};
      float wa[4] = {wv.x, wv.y, wv.z, wv.w};
      // rotate j by lane to cut write bank conflicts
#pragma unroll
      for (int jj = 0; jj < 4; ++jj) {
        int j = (jj + tid) & 3;
        float xe = (j == 0) ? xa[0] : (j == 1) ? xa[1] : (j == 2) ? xa[2] : xa[3];
        float we = (j == 0) ? wa[0] : (j == 1) ? wa[1] : (j == 2) ? wa[2] : wa[3];
        xs[c4 * 4 + j][row]  = xe;
        wsm[c4 * 4 + j][row] = we;
      }
    }
    __syncthreads();

    // ---- compute: 16 fp64 FMA per kk per thread ----
#pragma unroll 4
    for (int kk = 0; kk < DC; ++kk) {
      float4 xv = *(const float4*)&xs[kk][tr * 4];
      float4 wv = *(const float4*)&wsm[kk][tc * 4];
      const float xa[4] = {xv.x, xv.y, xv.z, xv.w};
      const float wa[4] = {wv.x, wv.y, wv.z, wv.w};
#pragma unroll
      for (int i = 0; i < 4; ++i) {
        double xd = (double)xa[i];
#pragma unroll
        for (int j = 0; j < 4; ++j)
          acc[i][j] = fma(xd, (double)wa[j], acc[i][j]);
      }
    }
    __syncthreads();
  }

  // ---- epilogue: add bias, cast fp32, coalesced float4 stores ----
  double b0 = (double)b[tc * 4 + 0];
  double b1 = (double)b[tc * 4 + 1];
  double b2 = (double)b[tc * 4 + 2];
  double b3 = (double)b[tc * 4 + 3];
#pragma unroll
  for (int i = 0; i < 4; ++i) {
    float4 o;
    o.x = (float)(acc[i][0] + b0);
    o.y = (float)(acc[i][1] + b1);
    o.z = (float)(acc[i][2] + b2);
    o.w = (float)(acc[i][3] + b3);
    *(float4*)(logits + (size_t)(tok0 + tr * 4 + i) * 64 + tc * 4) = o;
  }
}

// order-preserving float -> uint key (ascending float => ascending uint)
__device__ inline unsigned fkey(float f) {
  unsigned bits = __float_as_uint(f);
  return (bits & 0x80000000u) ? ~bits : (bits | 0x80000000u);
}

// ---------------------------------------------------------------------------
// Kernel 2: per-expert radix select — find exact key of the k-th largest
// logit in column e. 4 passes of 8-bit histograms, reading logits (L2-hot).
// ---------------------------------------------------------------------------
__global__ __launch_bounds__(256) void select_kernel(
    const float* __restrict__ logits, unsigned* __restrict__ ukeys,
    int N, int k) {
  __shared__ unsigned hist[256];
  __shared__ unsigned s_prefix, s_remaining;
  const int e = blockIdx.x;
  const int tid = threadIdx.x;

  if (tid == 0) { s_prefix = 0u; s_remaining = (unsigned)k; }

  for (int r = 0; r < 4; ++r) {
    int shift = 24 - 8 * r;
    unsigned maskhi = (r == 0) ? 0u : (0xFFFFFFFFu << (shift + 8));
    hist[tid] = 0u;
    __syncthreads();
    unsigned prefix = s_prefix;
    for (int i = tid; i < N; i += 256) {
      unsigned u = fkey(logits[(size_t)i * 64 + e]);
      if ((u & maskhi) == prefix)
        atomicAdd(&hist[(u >> shift) & 255u], 1u);
    }
    __syncthreads();
    if (tid == 0) {
      unsigned rem = s_remaining;
      unsigned cum = 0;
      int d = 255;
      for (; d > 0; --d) {
        cum += hist[d];
        if (cum >= rem) break;
        // if we fall through to d==0 the k-th is in bucket 0
      }
      if (cum < rem) cum += hist[0];  // d == 0 case
      s_remaining = rem - (cum - hist[d]);
      s_prefix = prefix | ((unsigned)d << shift);
    }
    __syncthreads();
  }
  if (tid == 0) ukeys[e] = s_prefix;
}

__global__ void init_counts(float* counts) { counts[threadIdx.x] = 0.0f; }

// ---------------------------------------------------------------------------
// Kernel 3: one wave per token. lane = expert. candidate iff key >= ukeys[e].
// Wave-max then ballot for (candidate && v == max) -> lowest expert index.
// ---------------------------------------------------------------------------
__global__ __launch_bounds__(256) void assign_kernel(
    const float* __restrict__ logits, const unsigned* __restrict__ ukeys,
    float* __restrict__ out, float* __restrict__ counts, int N) {
  const int lane = threadIdx.x & 63;
  const int token = blockIdx.x * 4 + (threadIdx.x >> 6);

  float v = logits[(size_t)token * 64 + lane];
  unsigned u = fkey(v);
  bool cand = (u >= ukeys[lane]);
  float cv = cand ? v : -INFINITY;
  float m = cv;
#pragma unroll
  for (int off = 32; off; off >>= 1) m = fmaxf(m, __shfl_xor(m, off));
  unsigned long long mask = __ballot(cand && (v == m));
  bool sel = (mask != 0ull);
  int minexp = sel ? (__ffsll((long long)mask) - 1) : -1;

  if (lane == 0) {
    out[token]         = sel ? m : 0.0f;
    out[N + token]     = (float)minexp;
    out[2 * N + token] = sel ? 1.0f : 0.0f;
  }
  if (sel && lane == minexp) atomicAdd(&counts[lane], 1.0f);
}

// ---------------------------------------------------------------------------
// Kernel 4: load-balance loss from counts (E=64), fp64 internally.
// ---------------------------------------------------------------------------
__global__ void loss_kernel(const float* __restrict__ counts,
                            float* __restrict__ out, int N) {
  if (threadIdx.x == 0) {
    double s = 0.0;
    for (int e = 0; e < 64; ++e) s += (double)counts[e];
    double mean = s / 64.0;
    double l = 0.0;
    for (int e = 0; e < 64; ++e) {
      double d = (double)counts[e] - mean;
      l += d * d;
    }
    l = (l / 64.0) / (mean + 1e-9);
    out[3 * (size_t)N] = (float)l;
  }
}

extern "C" void kernel_launch(void* const* d_in, const int* in_sizes, int n_in,
                              void* d_out, int out_size, void* d_ws, size_t ws_size,
                              hipStream_t stream) {
  const float* x = (const float*)d_in[0];
  const float* W = (const float*)d_in[1];
  const float* b = (const float*)d_in[2];
  // d_in[3] = detach_inputs: forward is identical either way.

  const int E = in_sizes[2];        // 64
  const int D = in_sizes[1] / E;    // 1024
  const int N = in_sizes[0] / D;    // 32768

  int k = (int)((double)N / (double)(E > 1 ? E : 1) * 1.2);
  if (k < 1) k = 1;
  if (k > N) k = N;                 // = 614 here

  float* logits   = (float*)d_ws;                       // N*E fp32 (8 MB)
  unsigned* ukeys = (unsigned*)(logits + (size_t)N * E);
  float* counts   = (float*)(ukeys + E);
  float* out      = (float*)d_out;

  logits_kernel<<<N / 64, 256, 0, stream>>>(x, W, b, logits, N, D);
  select_kernel<<<E, 256, 0, stream>>>(logits, ukeys, N, k);
  init_counts<<<1, 64, 0, stream>>>(counts);
  assign_kernel<<<N / 4, 256, 0, stream>>>(logits, ukeys, out, counts, N);
  loss_kernel<<<1, 64, 0, stream>>>(counts, out, N);
}

// Round 2
// 302.131 us; speedup vs baseline: 1.6705x; 1.6705x over previous
//
#include <hip/hip_runtime.h>
#include <math.h>

// ---------------------------------------------------------------------------
// Kernel 1: logits[N][64] = x[N][1024] @ W[64][1024]^T + b, fp64 accumulation.
// Writes BOTH row-major logits[N][E] (for assign) and transposed
// logitsT[E][N] (for coalesced per-expert selection). Values identical.
// ---------------------------------------------------------------------------
__global__ __launch_bounds__(256) void logits_kernel(
    const float* __restrict__ x, const float* __restrict__ W,
    const float* __restrict__ b, float* __restrict__ logits,
    float* __restrict__ logitsT, int N, int D) {
  const int DC = 128;
  __shared__ __attribute__((aligned(16))) float xs[128][68];
  __shared__ __attribute__((aligned(16))) float wsm[128][68];

  const int tid = threadIdx.x;
  const int tok0 = blockIdx.x * 64;
  const int tr = tid & 15;   // token group: tokens tr*4 .. tr*4+3
  const int tc = tid >> 4;   // expert group: experts tc*4 .. tc*4+3

  double acc[4][4];
#pragma unroll
  for (int i = 0; i < 4; ++i)
#pragma unroll
    for (int j = 0; j < 4; ++j) acc[i][j] = 0.0;

  for (int kc = 0; kc < D; kc += DC) {
    // ---- stage x-tile and W-tile (transposed) ----
#pragma unroll
    for (int it = 0; it < 8; ++it) {
      int idx4 = it * 256 + tid;       // 0..2047 float4 slots
      int row = idx4 >> 5;             // 0..63 (token / expert row)
      int c4  = idx4 & 31;             // float4 column within chunk
      float4 xv = *(const float4*)(x + (size_t)(tok0 + row) * D + kc + c4 * 4);
      float4 wv = *(const float4*)(W + (size_t)row * D + kc + c4 * 4);
      float xa[4] = {xv.x, xv.y, xv.z, xv.w};
      float wa[4] = {wv.x, wv.y, wv.z, wv.w};
#pragma unroll
      for (int jj = 0; jj < 4; ++jj) {
        int j = (jj + tid) & 3;
        float xe = (j == 0) ? xa[0] : (j == 1) ? xa[1] : (j == 2) ? xa[2] : xa[3];
        float we = (j == 0) ? wa[0] : (j == 1) ? wa[1] : (j == 2) ? wa[2] : wa[3];
        xs[c4 * 4 + j][row]  = xe;
        wsm[c4 * 4 + j][row] = we;
      }
    }
    __syncthreads();

    // ---- compute: 16 fp64 FMA per kk per thread ----
#pragma unroll 4
    for (int kk = 0; kk < DC; ++kk) {
      float4 xv = *(const float4*)&xs[kk][tr * 4];
      float4 wv = *(const float4*)&wsm[kk][tc * 4];
      const float xa[4] = {xv.x, xv.y, xv.z, xv.w};
      const float wa[4] = {wv.x, wv.y, wv.z, wv.w};
#pragma unroll
      for (int i = 0; i < 4; ++i) {
        double xd = (double)xa[i];
#pragma unroll
        for (int j = 0; j < 4; ++j)
          acc[i][j] = fma(xd, (double)wa[j], acc[i][j]);
      }
    }
    __syncthreads();
  }

  // ---- epilogue: add bias, cast fp32, store both layouts ----
  double bb[4] = {(double)b[tc * 4 + 0], (double)b[tc * 4 + 1],
                  (double)b[tc * 4 + 2], (double)b[tc * 4 + 3]};
  float f[4][4];
#pragma unroll
  for (int i = 0; i < 4; ++i)
#pragma unroll
    for (int j = 0; j < 4; ++j) f[i][j] = (float)(acc[i][j] + bb[j]);

#pragma unroll
  for (int i = 0; i < 4; ++i) {
    float4 o = {f[i][0], f[i][1], f[i][2], f[i][3]};
    *(float4*)(logits + (size_t)(tok0 + tr * 4 + i) * 64 + tc * 4) = o;
  }
#pragma unroll
  for (int j = 0; j < 4; ++j) {
    float4 o = {f[0][j], f[1][j], f[2][j], f[3][j]};
    *(float4*)(logitsT + (size_t)(tc * 4 + j) * N + tok0 + tr * 4) = o;
  }
}

// order-preserving float -> uint key (ascending float => ascending uint)
__device__ inline unsigned fkey(float f) {
  unsigned bits = __float_as_uint(f);
  return (bits & 0x80000000u) ? ~bits : (bits | 0x80000000u);
}

// ---------------------------------------------------------------------------
// Kernel 2: per-expert radix select, register-resident.
// One 1024-thread block per expert; each thread holds 32 keys in registers
// (single coalesced read of the contiguous logitsT column). 4x 8-bit passes
// over registers with per-wave replicated LDS histograms; descending scan
// done by wave 0 via shuffle suffix-scan.
// ---------------------------------------------------------------------------
__global__ __launch_bounds__(1024) void select_kernel(
    const float* __restrict__ logitsT, unsigned* __restrict__ ukeys,
    int N, int k) {
  __shared__ unsigned hist[16][256];
  __shared__ unsigned s_prefix, s_rem;
  const int e = blockIdx.x;
  const int tid = threadIdx.x;
  const int wid = tid >> 6;

  unsigned key[32];
  const float4* src = (const float4*)(logitsT + (size_t)e * N);
#pragma unroll
  for (int i = 0; i < 8; ++i) {
    float4 v = src[tid + i * 1024];
    key[i * 4 + 0] = fkey(v.x);
    key[i * 4 + 1] = fkey(v.y);
    key[i * 4 + 2] = fkey(v.z);
    key[i * 4 + 3] = fkey(v.w);
  }
  if (tid == 0) { s_prefix = 0u; s_rem = (unsigned)k; }

  for (int r = 0; r < 4; ++r) {
    const int shift = 24 - 8 * r;
    const unsigned maskhi = (r == 0) ? 0u : (0xFFFFFFFFu << (shift + 8));
    // zero all 16 histograms
#pragma unroll
    for (int z = 0; z < 4; ++z) ((unsigned*)hist)[z * 1024 + tid] = 0u;
    __syncthreads();
    const unsigned prefix = s_prefix;
#pragma unroll
    for (int i = 0; i < 32; ++i) {
      unsigned u = key[i];
      if ((u & maskhi) == prefix)
        atomicAdd(&hist[wid][(u >> shift) & 255u], 1u);
    }
    __syncthreads();
    if (tid < 64) {
      unsigned rem = s_rem;
      // lane owns bins tid*4 .. tid*4+3 (higher bin = larger value)
      unsigned h0 = 0, h1 = 0, h2 = 0, h3 = 0;
#pragma unroll
      for (int w = 0; w < 16; ++w) {
        h0 += hist[w][tid * 4 + 0];
        h1 += hist[w][tid * 4 + 1];
        h2 += hist[w][tid * 4 + 2];
        h3 += hist[w][tid * 4 + 3];
      }
      unsigned c3 = h3, c2 = c3 + h2, c1 = c2 + h1, c0 = c1 + h0;
      unsigned cum = c0;  // inclusive suffix over lanes >= tid
#pragma unroll
      for (int off = 1; off < 64; off <<= 1) {
        unsigned v = __shfl_down(cum, off);
        if (tid + off < 64) cum += v;
      }
      unsigned above = cum - c0;  // count in lanes > tid
      if (above < rem && rem <= cum) {  // crossing happens in this lane
        int j; unsigned abv;
        if (above + c3 >= rem)      { j = 3; abv = above; }
        else if (above + c2 >= rem) { j = 2; abv = above + c3; }
        else if (above + c1 >= rem) { j = 1; abv = above + c2; }
        else                        { j = 0; abv = above + c1; }
        s_rem = rem - abv;
        s_prefix = prefix | ((unsigned)(tid * 4 + j) << shift);
      }
    }
    __syncthreads();
  }
  if (tid == 0) ukeys[e] = s_prefix;
}

__global__ void init_counts(float* counts) { counts[threadIdx.x] = 0.0f; }

// ---------------------------------------------------------------------------
// Kernel 3: one wave per token. lane = expert. candidate iff key >= ukeys[e].
// ---------------------------------------------------------------------------
__global__ __launch_bounds__(256) void assign_kernel(
    const float* __restrict__ logits, const unsigned* __restrict__ ukeys,
    float* __restrict__ out, float* __restrict__ counts, int N) {
  const int lane = threadIdx.x & 63;
  const int token = blockIdx.x * 4 + (threadIdx.x >> 6);

  float v = logits[(size_t)token * 64 + lane];
  unsigned u = fkey(v);
  bool cand = (u >= ukeys[lane]);
  float cv = cand ? v : -INFINITY;
  float m = cv;
#pragma unroll
  for (int off = 32; off; off >>= 1) m = fmaxf(m, __shfl_xor(m, off));
  unsigned long long mask = __ballot(cand && (v == m));
  bool sel = (mask != 0ull);
  int minexp = sel ? (__ffsll((long long)mask) - 1) : -1;

  if (lane == 0) {
    out[token]         = sel ? m : 0.0f;
    out[N + token]     = (float)minexp;
    out[2 * N + token] = sel ? 1.0f : 0.0f;
  }
  if (sel && lane == minexp) atomicAdd(&counts[lane], 1.0f);
}

// ---------------------------------------------------------------------------
// Kernel 4: load-balance loss from counts (E=64), fp64 internally.
// ---------------------------------------------------------------------------
__global__ void loss_kernel(const float* __restrict__ counts,
                            float* __restrict__ out, int N) {
  if (threadIdx.x == 0) {
    double s = 0.0;
    for (int e = 0; e < 64; ++e) s += (double)counts[e];
    double mean = s / 64.0;
    double l = 0.0;
    for (int e = 0; e < 64; ++e) {
      double d = (double)counts[e] - mean;
      l += d * d;
    }
    l = (l / 64.0) / (mean + 1e-9);
    out[3 * (size_t)N] = (float)l;
  }
}

extern "C" void kernel_launch(void* const* d_in, const int* in_sizes, int n_in,
                              void* d_out, int out_size, void* d_ws, size_t ws_size,
                              hipStream_t stream) {
  const float* x = (const float*)d_in[0];
  const float* W = (const float*)d_in[1];
  const float* b = (const float*)d_in[2];

  const int E = in_sizes[2];        // 64
  const int D = in_sizes[1] / E;    // 1024
  const int N = in_sizes[0] / D;    // 32768

  int k = (int)((double)N / (double)(E > 1 ? E : 1) * 1.2);
  if (k < 1) k = 1;
  if (k > N) k = N;                 // = 614 here

  float* logits   = (float*)d_ws;                          // N*E fp32 (8 MB)
  float* logitsT  = logits + (size_t)N * E;                // N*E fp32 (8 MB)
  unsigned* ukeys = (unsigned*)(logitsT + (size_t)N * E);
  float* counts   = (float*)(ukeys + E);
  float* out      = (float*)d_out;

  logits_kernel<<<N / 64, 256, 0, stream>>>(x, W, b, logits, logitsT, N, D);
  select_kernel<<<E, 1024, 0, stream>>>(logitsT, ukeys, N, k);
  init_counts<<<1, 64, 0, stream>>>(counts);
  assign_kernel<<<N / 4, 256, 0, stream>>>(logits, ukeys, out, counts, N);
  loss_kernel<<<1, 64, 0, stream>>>(counts, out, N);
}